// Round 2
// baseline (715.816 us; speedup 1.0000x reference)
//
#include <hip/hip_runtime.h>
#include <hip/hip_bf16.h>

// ---------------------------------------------------------------------------
// AttnBlock: GroupNorm -> q,k,v 1x1conv -> softmax(QK^T*scale)@V -> proj + res
// B=4, H=W=64 (HW=4096), C=512, G=32 (16 ch/group). All fp32 in/out.
// Strategy: bf16 MFMA (16x16x32) for all GEMMs; fp32 accumulation; fp32 GN
// and softmax. Classic (non-flash) attention; P written in-place over S.
// ---------------------------------------------------------------------------

typedef __attribute__((ext_vector_type(8))) short s16x8;  // 8 bf16 (4 VGPRs)
typedef __attribute__((ext_vector_type(4))) float f32x4;  // MFMA accum

__device__ inline ushort f2bf(float f) {
    union { float f; unsigned u; } v; v.f = f;
    unsigned r = (v.u + 0x7FFFu + ((v.u >> 16) & 1u)) >> 16;
    return (ushort)r;
}

__device__ inline void gll16(const void* g, void* l) {
    __builtin_amdgcn_global_load_lds(
        (const __attribute__((address_space(1))) void*)g,
        (__attribute__((address_space(3))) void*)l, 16, 0, 0);
}

// ---------------------------------------------------------------------------
// GroupNorm stats: one block per (b,g). Reduces 4096 pixels x 16 channels.
// ---------------------------------------------------------------------------
__global__ __launch_bounds__(256) void gn_stats(const float* __restrict__ x,
                                                float2* __restrict__ stats) {
    int bg = blockIdx.x;
    int b = bg >> 5, g = bg & 31;
    const float* base = x + (size_t)b * 4096 * 512 + g * 16;
    int t = threadIdx.x;
    float s = 0.f, ss = 0.f;
    for (int i = t; i < 16384; i += 256) {   // 4096 pixels * 4 float4-quads
        int pix = i >> 2, quad = i & 3;
        float4 v = *(const float4*)(base + (size_t)pix * 512 + quad * 4);
        s  += v.x + v.y + v.z + v.w;
        ss += v.x * v.x + v.y * v.y + v.z * v.z + v.w * v.w;
    }
    for (int off = 32; off > 0; off >>= 1) {
        s  += __shfl_xor(s, off);
        ss += __shfl_xor(ss, off);
    }
    __shared__ float rs[4], rss[4];
    int w = t >> 6, lane = t & 63;
    if (lane == 0) { rs[w] = s; rss[w] = ss; }
    __syncthreads();
    if (t == 0) {
        float S1 = rs[0] + rs[1] + rs[2] + rs[3];
        float S2 = rss[0] + rss[1] + rss[2] + rss[3];
        float mean = S1 * (1.f / 65536.f);
        float var  = S2 * (1.f / 65536.f) - mean * mean;
        stats[bg] = make_float2(mean, rsqrtf(var + 1e-5f));
    }
}

// ---------------------------------------------------------------------------
// GroupNorm apply + cast to bf16 h_
// ---------------------------------------------------------------------------
__global__ __launch_bounds__(256) void gn_apply(const float* __restrict__ x,
                                                const float* __restrict__ gamma,
                                                const float* __restrict__ beta,
                                                const float2* __restrict__ stats,
                                                ushort* __restrict__ h) {
    const int total = 4 * 4096 * 512 / 4;   // float4 units
    for (int i = blockIdx.x * blockDim.x + threadIdx.x; i < total;
         i += gridDim.x * blockDim.x) {
        int e = i * 4;
        int c = e & 511;
        int bp = e >> 9;          // b*4096 + pixel
        int b = bp >> 12;
        int g = c >> 4;
        float2 st = stats[b * 32 + g];
        float4 v  = *(const float4*)(x + (size_t)e);
        float4 ga = *(const float4*)(gamma + c);
        float4 be = *(const float4*)(beta + c);
        ushort4 o;
        o.x = f2bf((v.x - st.x) * st.y * ga.x + be.x);
        o.y = f2bf((v.y - st.x) * st.y * ga.y + be.y);
        o.z = f2bf((v.z - st.x) * st.y * ga.z + be.z);
        o.w = f2bf((v.w - st.x) * st.y * ga.w + be.w);
        ((ushort4*)h)[i] = o;
    }
}

// ---------------------------------------------------------------------------
// Weight prep: 512x512 fp32 (K,N) -> bf16 transposed (N,K)
// ---------------------------------------------------------------------------
__global__ void prep_w(const float* __restrict__ wq, const float* __restrict__ wk,
                       const float* __restrict__ wv, const float* __restrict__ wp,
                       ushort* __restrict__ oq, ushort* __restrict__ ok,
                       ushort* __restrict__ ov, ushort* __restrict__ op) {
    const float* src; ushort* dst;
    switch (blockIdx.z) {
        case 0: src = wq; dst = oq; break;
        case 1: src = wk; dst = ok; break;
        case 2: src = wv; dst = ov; break;
        default: src = wp; dst = op; break;
    }
    __shared__ float tile[32][33];
    int k0 = blockIdx.y * 32, n0 = blockIdx.x * 32;
    int tx = threadIdx.x, ty = threadIdx.y;   // (32,8)
    #pragma unroll
    for (int i = 0; i < 4; i++)
        tile[ty + i * 8][tx] = src[(size_t)(k0 + ty + i * 8) * 512 + n0 + tx];
    __syncthreads();
    #pragma unroll
    for (int i = 0; i < 4; i++)
        dst[(size_t)(n0 + ty + i * 8) * 512 + k0 + tx] = f2bf(tile[tx][ty + i * 8]);
}

// ---------------------------------------------------------------------------
// V transpose per batch: (4096 x 512) -> (512 x 4096), bf16
// ---------------------------------------------------------------------------
__global__ __launch_bounds__(256) void transpose_v(const ushort* __restrict__ v,
                                                   ushort* __restrict__ vt) {
    __shared__ ushort tile[64][72];
    int b = blockIdx.z;
    int kv0 = blockIdx.x * 64, c0 = blockIdx.y * 64;
    const ushort* in = v + (size_t)b * 4096 * 512;
    ushort* out = vt + (size_t)b * 512 * 4096;
    int t = threadIdx.x;
    int c4 = t & 15, r = t >> 4;
    #pragma unroll
    for (int i = 0; i < 4; i++) {
        int row = r + i * 16;
        *(ushort4*)&tile[row][c4 * 4] =
            *(const ushort4*)(in + (size_t)(kv0 + row) * 512 + c0 + c4 * 4);
    }
    __syncthreads();
    int kv4 = t & 15, rc = t >> 4;
    #pragma unroll
    for (int i = 0; i < 4; i++) {
        int c = rc + i * 16;
        ushort4 o;
        o.x = tile[kv4 * 4 + 0][c];
        o.y = tile[kv4 * 4 + 1][c];
        o.z = tile[kv4 * 4 + 2][c];
        o.w = tile[kv4 * 4 + 3][c];
        *(ushort4*)(out + (size_t)(c0 + c) * 4096 + kv0 + kv4 * 4) = o;
    }
}

// ---------------------------------------------------------------------------
// Generic GEMM: C[m,n] = (sum_k A[m,k]*Bt[n,k] + bias[n]) * alpha (+ res)
// A: MxK bf16 (row stride lda), Bt: NxK bf16 (row stride K).
// 128x128 tile, BK=32, 256 thr (4 waves 2x2).
// ---------------------------------------------------------------------------
template<bool OUT_BF16, bool RES, bool HAS_BIAS>
__global__ __launch_bounds__(256, 2) void gemm_bt(
    const ushort* __restrict__ A, int lda, const ushort* __restrict__ Bt,
    const float* __restrict__ bias, const float* __restrict__ res,
    void* __restrict__ Cv, int M, int N, int K, float alpha) {
    __shared__ ushort As[128 * 32];
    __shared__ ushort Bs[128 * 32];
    int t = threadIdx.x;
    int m0 = blockIdx.y * 128, n0 = blockIdx.x * 128;
    int lane = t & 63, w = t >> 6, wr = w >> 1, wc = w & 1;

    // staging: each thread stages 2x16B into As and Bs (linear LDS order)
    int rowS = (t * 8) >> 5;        // 0..63
    int kkS  = (t * 8) & 31;
    const ushort* gA0 = A  + (size_t)(m0 + rowS) * lda + kkS;
    const ushort* gA1 = A  + (size_t)(m0 + rowS + 64) * lda + kkS;
    const ushort* gB0 = Bt + (size_t)(n0 + rowS) * K + kkS;
    const ushort* gB1 = Bt + (size_t)(n0 + rowS + 64) * K + kkS;
    ushort* lA0 = As + t * 8;  ushort* lA1 = As + 2048 + t * 8;
    ushort* lB0 = Bs + t * 8;  ushort* lB1 = Bs + 2048 + t * 8;

    f32x4 acc[4][4];
    #pragma unroll
    for (int i = 0; i < 4; i++)
        #pragma unroll
        for (int j = 0; j < 4; j++) acc[i][j] = (f32x4){0.f, 0.f, 0.f, 0.f};

    int kfr = (lane >> 4) * 8;
    int rA = wr * 64 + (lane & 15);
    int rB = wc * 64 + (lane & 15);

    for (int kt = 0; kt < K; kt += 32) {
        gll16(gA0 + kt, lA0); gll16(gA1 + kt, lA1);
        gll16(gB0 + kt, lB0); gll16(gB1 + kt, lB1);
        __syncthreads();
        s16x8 a[4], b[4];
        #pragma unroll
        for (int i = 0; i < 4; i++)
            a[i] = *(const s16x8*)&As[(rA + i * 16) * 32 + kfr];
        #pragma unroll
        for (int i = 0; i < 4; i++)
            b[i] = *(const s16x8*)&Bs[(rB + i * 16) * 32 + kfr];
        #pragma unroll
        for (int mi = 0; mi < 4; mi++)
            #pragma unroll
            for (int ni = 0; ni < 4; ni++)
                acc[mi][ni] = __builtin_amdgcn_mfma_f32_16x16x32_bf16(
                    a[mi], b[ni], acc[mi][ni], 0, 0, 0);
        __syncthreads();
    }

    float* Cf = (float*)Cv;
    ushort* Cb = (ushort*)Cv;
    #pragma unroll
    for (int ni = 0; ni < 4; ni++) {
        int col = n0 + wc * 64 + ni * 16 + (lane & 15);
        float bv_ = HAS_BIAS ? bias[col] : 0.f;
        #pragma unroll
        for (int mi = 0; mi < 4; mi++) {
            int rowb = m0 + wr * 64 + mi * 16 + (lane >> 4) * 4;
            #pragma unroll
            for (int r = 0; r < 4; r++) {
                size_t off = (size_t)(rowb + r) * N + col;
                float vout = (acc[mi][ni][r] + bv_) * alpha;
                if (RES) vout += res[off];
                if (OUT_BF16) Cb[off] = f2bf(vout);
                else         Cf[off] = vout;
            }
        }
    }
}

// ---------------------------------------------------------------------------
// Row softmax: S (row x 4096 fp32) -> P bf16 written IN-PLACE into the first
// half of the same fp32 row (P row stride = 8192 ushorts). One block per row.
// ---------------------------------------------------------------------------
__global__ __launch_bounds__(256) void softmax_rows(float* __restrict__ S) {
    int row = blockIdx.x;
    const float4* src = (const float4*)(S + (size_t)row * 4096);
    int t = threadIdx.x;
    float4 v[4];
    #pragma unroll
    for (int i = 0; i < 4; i++) v[i] = src[t + i * 256];

    float m = -1e30f;
    #pragma unroll
    for (int i = 0; i < 4; i++)
        m = fmaxf(m, fmaxf(fmaxf(v[i].x, v[i].y), fmaxf(v[i].z, v[i].w)));
    for (int off = 32; off > 0; off >>= 1) m = fmaxf(m, __shfl_xor(m, off));
    __shared__ float red1[4], red2[4];
    int w = t >> 6, lane = t & 63;
    if (lane == 0) red1[w] = m;
    __syncthreads();
    m = fmaxf(fmaxf(red1[0], red1[1]), fmaxf(red1[2], red1[3]));

    float s = 0.f;
    #pragma unroll
    for (int i = 0; i < 4; i++) {
        v[i].x = __expf(v[i].x - m); v[i].y = __expf(v[i].y - m);
        v[i].z = __expf(v[i].z - m); v[i].w = __expf(v[i].w - m);
        s += v[i].x + v[i].y + v[i].z + v[i].w;
    }
    for (int off = 32; off > 0; off >>= 1) s += __shfl_xor(s, off);
    if (lane == 0) red2[w] = s;
    __syncthreads();
    s = red2[0] + red2[1] + red2[2] + red2[3];
    float inv = 1.f / s;

    // all reads of this row completed before the barriers above
    ushort4* dst = (ushort4*)((ushort*)S + (size_t)row * 8192);
    #pragma unroll
    for (int i = 0; i < 4; i++) {
        ushort4 o;
        o.x = f2bf(v[i].x * inv); o.y = f2bf(v[i].y * inv);
        o.z = f2bf(v[i].z * inv); o.w = f2bf(v[i].w * inv);
        dst[t + i * 256] = o;
    }
}

// ---------------------------------------------------------------------------
extern "C" void kernel_launch(void* const* d_in, const int* in_sizes, int n_in,
                              void* d_out, int out_size, void* d_ws, size_t ws_size,
                              hipStream_t stream) {
    const float* x     = (const float*)d_in[0];
    const float* gamma = (const float*)d_in[1];
    const float* beta  = (const float*)d_in[2];
    const float* wq = (const float*)d_in[3];  const float* bq = (const float*)d_in[4];
    const float* wk = (const float*)d_in[5];  const float* bk = (const float*)d_in[6];
    const float* wv = (const float*)d_in[7];  const float* bv = (const float*)d_in[8];
    const float* wp = (const float*)d_in[9];  const float* bp = (const float*)d_in[10];
    float* out = (float*)d_out;

    char* ws = (char*)d_ws;
    size_t off = 0;
    auto alloc = [&](size_t bytes) {
        void* p = ws + off;
        off += (bytes + 255) & ~(size_t)255;
        return p;
    };
    const size_t MTOK = (size_t)4 * 4096;      // 16384 rows
    const size_t QO   = (size_t)4096 * 512;    // per-batch elems

    float2* stats = (float2*)alloc(128 * sizeof(float2));
    ushort* wtq = (ushort*)alloc(512 * 512 * 2);
    ushort* wtk = (ushort*)alloc(512 * 512 * 2);
    ushort* wtv = (ushort*)alloc(512 * 512 * 2);
    ushort* wtp = (ushort*)alloc(512 * 512 * 2);
    ushort* hb  = (ushort*)alloc(MTOK * 512 * 2);
    ushort* qb  = (ushort*)alloc(MTOK * 512 * 2);
    ushort* kb  = (ushort*)alloc(MTOK * 512 * 2);
    ushort* vb  = (ushort*)alloc(MTOK * 512 * 2);
    ushort* vtb = (ushort*)alloc(MTOK * 512 * 2);
    float*  Sb  = (float*)alloc((size_t)4096 * 4096 * 4);
    ushort* aob = hb;   // h_ is dead after the V GEMM; reuse for attn output
    (void)ws_size; (void)in_sizes; (void)n_in; (void)out_size;

    gn_stats<<<128, 256, 0, stream>>>(x, stats);
    gn_apply<<<2048, 256, 0, stream>>>(x, gamma, beta, stats, hb);
    prep_w<<<dim3(16, 16, 4), dim3(32, 8), 0, stream>>>(wq, wk, wv, wp,
                                                        wtq, wtk, wtv, wtp);
    const float scale = 0.044194173824159216f;   // 512^-0.5, folded into q
    gemm_bt<true, false, true><<<dim3(4, 128), 256, 0, stream>>>(
        hb, 512, wtq, bq, nullptr, qb, 16384, 512, 512, scale);
    gemm_bt<true, false, true><<<dim3(4, 128), 256, 0, stream>>>(
        hb, 512, wtk, bk, nullptr, kb, 16384, 512, 512, 1.f);
    gemm_bt<true, false, true><<<dim3(4, 128), 256, 0, stream>>>(
        hb, 512, wtv, bv, nullptr, vb, 16384, 512, 512, 1.f);
    transpose_v<<<dim3(64, 8, 4), 256, 0, stream>>>(vb, vtb);

    for (int b = 0; b < 4; b++) {
        gemm_bt<false, false, false><<<dim3(32, 32), 256, 0, stream>>>(
            qb + b * QO, 512, kb + b * QO, nullptr, nullptr, Sb,
            4096, 4096, 512, 1.f);
        softmax_rows<<<4096, 256, 0, stream>>>(Sb);
        gemm_bt<true, false, false><<<dim3(4, 32), 256, 0, stream>>>(
            (const ushort*)Sb, 8192, vtb + b * QO, nullptr, nullptr,
            aob + b * QO, 4096, 512, 4096, 1.f);
    }
    gemm_bt<false, true, true><<<dim3(4, 128), 256, 0, stream>>>(
        aob, 512, wtp, bp, x, out, 16384, 512, 512, 1.f);
}

// Round 3
// 477.392 us; speedup vs baseline: 1.4994x; 1.4994x over previous
//
#include <hip/hip_runtime.h>
#include <hip/hip_bf16.h>

// ---------------------------------------------------------------------------
// AttnBlock: GroupNorm -> q,k,v 1x1conv -> softmax(QK^T*scale)@V -> proj + res
// B=4, HW=4096, C=512, G=32. bf16 MFMA GEMMs, fp32 accum.
// Round 3: 2-phase double-buffered GEMM pipeline, z-batched attention (pairs),
// bf16 S with in-place softmax, BM=64 PV tile, 2-stage GroupNorm.
// ---------------------------------------------------------------------------

typedef __attribute__((ext_vector_type(8))) short s16x8;  // 8 bf16
typedef __attribute__((ext_vector_type(4))) float f32x4;  // MFMA accum

__device__ inline ushort f2bf(float f) {
    union { float f; unsigned u; } v; v.f = f;
    unsigned r = (v.u + 0x7FFFu + ((v.u >> 16) & 1u)) >> 16;
    return (ushort)r;
}
__device__ inline float bf2f(ushort u) {
    union { unsigned u; float f; } v; v.u = ((unsigned)u) << 16;
    return v.f;
}

__device__ inline void gll16(const void* g, void* l) {
    __builtin_amdgcn_global_load_lds(
        (const __attribute__((address_space(1))) void*)g,
        (__attribute__((address_space(3))) void*)l, 16, 0, 0);
}

// ---------------------------------------------------------------------------
// GroupNorm stage 1: contiguous partial sums. 256 blocks (4 batch x 64 chunks
// of 64 pixels). Thread t: channel-quad t&127, pixel parity t>>7.
// ---------------------------------------------------------------------------
__global__ __launch_bounds__(256) void gn_part(const float* __restrict__ x,
                                               float2* __restrict__ partial) {
    int blk = blockIdx.x;
    int b = blk >> 6, chunk = blk & 63;
    const float* base = x + ((size_t)b * 4096 + chunk * 64) * 512;
    int t = threadIdx.x;
    int q = t & 127, ph = t >> 7;
    float s = 0.f, ss = 0.f;
    for (int p = ph; p < 64; p += 2) {
        float4 v = *(const float4*)(base + (size_t)p * 512 + q * 4);
        s  += v.x + v.y + v.z + v.w;
        ss += v.x * v.x + v.y * v.y + v.z * v.z + v.w * v.w;
    }
    __shared__ float ls[256], lss[256];
    ls[t] = s; lss[t] = ss;
    __syncthreads();
    if (t < 32) {   // group t: quads 4t..4t+3, both pixel halves
        float S1 = 0.f, S2 = 0.f;
        #pragma unroll
        for (int j = 0; j < 4; j++) {
            int i = t * 4 + j;
            S1 += ls[i] + ls[i + 128];
            S2 += lss[i] + lss[i + 128];
        }
        partial[(size_t)blk * 32 + t] = make_float2(S1, S2);
    }
}

__global__ void gn_reduce(const float2* __restrict__ partial,
                          float2* __restrict__ stats) {
    int i = threadIdx.x;   // b*32+g
    if (i < 128) {
        int b = i >> 5, g = i & 31;
        float S1 = 0.f, S2 = 0.f;
        for (int c = 0; c < 64; c++) {
            float2 p = partial[((size_t)(b * 64 + c)) * 32 + g];
            S1 += p.x; S2 += p.y;
        }
        float mean = S1 * (1.f / 65536.f);
        float var  = S2 * (1.f / 65536.f) - mean * mean;
        stats[i] = make_float2(mean, rsqrtf(var + 1e-5f));
    }
}

// ---------------------------------------------------------------------------
// GroupNorm apply + cast to bf16 h_
// ---------------------------------------------------------------------------
__global__ __launch_bounds__(256) void gn_apply(const float* __restrict__ x,
                                                const float* __restrict__ gamma,
                                                const float* __restrict__ beta,
                                                const float2* __restrict__ stats,
                                                ushort* __restrict__ h) {
    const int total = 4 * 4096 * 512 / 4;
    for (int i = blockIdx.x * blockDim.x + threadIdx.x; i < total;
         i += gridDim.x * blockDim.x) {
        int e = i * 4;
        int c = e & 511;
        int b = e >> 21;           // e / (4096*512)
        int g = c >> 4;
        float2 st = stats[b * 32 + g];
        float4 v  = *(const float4*)(x + (size_t)e);
        float4 ga = *(const float4*)(gamma + c);
        float4 be = *(const float4*)(beta + c);
        ushort4 o;
        o.x = f2bf((v.x - st.x) * st.y * ga.x + be.x);
        o.y = f2bf((v.y - st.x) * st.y * ga.y + be.y);
        o.z = f2bf((v.z - st.x) * st.y * ga.z + be.z);
        o.w = f2bf((v.w - st.x) * st.y * ga.w + be.w);
        ((ushort4*)h)[i] = o;
    }
}

// ---------------------------------------------------------------------------
// Weight prep: 512x512 fp32 (K,N) -> bf16 transposed (N,K)
// ---------------------------------------------------------------------------
__global__ void prep_w(const float* __restrict__ wq, const float* __restrict__ wk,
                       const float* __restrict__ wv, const float* __restrict__ wp,
                       ushort* __restrict__ oq, ushort* __restrict__ ok,
                       ushort* __restrict__ ov, ushort* __restrict__ op) {
    const float* src; ushort* dst;
    switch (blockIdx.z) {
        case 0: src = wq; dst = oq; break;
        case 1: src = wk; dst = ok; break;
        case 2: src = wv; dst = ov; break;
        default: src = wp; dst = op; break;
    }
    __shared__ float tile[32][33];
    int k0 = blockIdx.y * 32, n0 = blockIdx.x * 32;
    int tx = threadIdx.x, ty = threadIdx.y;
    #pragma unroll
    for (int i = 0; i < 4; i++)
        tile[ty + i * 8][tx] = src[(size_t)(k0 + ty + i * 8) * 512 + n0 + tx];
    __syncthreads();
    #pragma unroll
    for (int i = 0; i < 4; i++)
        dst[(size_t)(n0 + ty + i * 8) * 512 + k0 + tx] = f2bf(tile[tx][ty + i * 8]);
}

// ---------------------------------------------------------------------------
// V transpose per batch: (4096 x 512) -> (512 x 4096), bf16
// ---------------------------------------------------------------------------
__global__ __launch_bounds__(256) void transpose_v(const ushort* __restrict__ v,
                                                   ushort* __restrict__ vt) {
    __shared__ ushort tile[64][72];
    int b = blockIdx.z;
    int kv0 = blockIdx.x * 64, c0 = blockIdx.y * 64;
    const ushort* in = v + (size_t)b * 4096 * 512;
    ushort* out = vt + (size_t)b * 512 * 4096;
    int t = threadIdx.x;
    int c4 = t & 15, r = t >> 4;
    #pragma unroll
    for (int i = 0; i < 4; i++) {
        int row = r + i * 16;
        *(ushort4*)&tile[row][c4 * 4] =
            *(const ushort4*)(in + (size_t)(kv0 + row) * 512 + c0 + c4 * 4);
    }
    __syncthreads();
    int kv4 = t & 15, rc = t >> 4;
    #pragma unroll
    for (int i = 0; i < 4; i++) {
        int c = rc + i * 16;
        ushort4 o;
        o.x = tile[kv4 * 4 + 0][c];
        o.y = tile[kv4 * 4 + 1][c];
        o.z = tile[kv4 * 4 + 2][c];
        o.w = tile[kv4 * 4 + 3][c];
        *(ushort4*)(out + (size_t)(c0 + c) * 4096 + kv0 + kv4 * 4) = o;
    }
}

// ---------------------------------------------------------------------------
// 2-phase double-buffered GEMM: C[z][m,n] = (sum_k A[z][m,k]*Bt[z][n,k] +
// bias[n]) * alpha (+ res). BM x 128 tile, BK=32, 256 thr (4 waves 2x2).
// Pipeline: STAGE(t+1) issued before compute(t); single barrier per iter
// (its implicit vmcnt(0) drain lands after the MFMAs -> latency hidden).
// ---------------------------------------------------------------------------
template<int BM, bool OUT_BF16, bool RES, bool HAS_BIAS>
__global__ __launch_bounds__(256, 3) void gemm_bt(
    const ushort* __restrict__ A, int lda, long long sA,
    const ushort* __restrict__ Bt, long long sB,
    const float* __restrict__ bias, const float* __restrict__ res,
    void* __restrict__ Cv, long long sC,
    int M, int N, int K, float alpha) {
    constexpr int MFR   = BM / 32;   // M fragments per wave
    constexpr int WROWS = BM / 2;    // rows per wave
    __shared__ ushort As[2][BM * 32];
    __shared__ ushort Bs[2][128 * 32];
    int t = threadIdx.x;
    int z = blockIdx.z;
    const ushort* Ab = A  + (size_t)z * sA;
    const ushort* Bb = Bt + (size_t)z * sB;
    int m0 = blockIdx.y * BM, n0 = blockIdx.x * 128;
    int lane = t & 63, w = t >> 6, wr = w >> 1, wc = w & 1;

    int rowS = (t * 8) >> 5;
    int kkS  = (t * 8) & 31;
    const ushort* gA0 = Ab + (size_t)(m0 + rowS) * lda + kkS;
    const ushort* gA1 = Ab + (size_t)(m0 + rowS + 64) * lda + kkS;  // BM==128
    const ushort* gB0 = Bb + (size_t)(n0 + rowS) * K + kkS;
    const ushort* gB1 = Bb + (size_t)(n0 + rowS + 64) * K + kkS;

    f32x4 acc[MFR][4];
    #pragma unroll
    for (int i = 0; i < MFR; i++)
        #pragma unroll
        for (int j = 0; j < 4; j++) acc[i][j] = (f32x4){0.f, 0.f, 0.f, 0.f};

    int kfr = (lane >> 4) * 8;
    int rA = wr * WROWS + (lane & 15);
    int rB = wc * 64 + (lane & 15);
    int NT = K >> 5;

    auto stage = [&](int kt, int buf) {
        int ko = kt * 32;
        gll16(gA0 + ko, &As[buf][t * 8]);
        if constexpr (BM == 128) gll16(gA1 + ko, &As[buf][2048 + t * 8]);
        gll16(gB0 + ko, &Bs[buf][t * 8]);
        gll16(gB1 + ko, &Bs[buf][2048 + t * 8]);
    };

    stage(0, 0);
    __syncthreads();
    for (int kt = 0; kt < NT; ++kt) {
        int cur = kt & 1;
        if (kt + 1 < NT) stage(kt + 1, cur ^ 1);
        s16x8 a[MFR], b[4];
        #pragma unroll
        for (int i = 0; i < MFR; i++)
            a[i] = *(const s16x8*)&As[cur][(rA + i * 16) * 32 + kfr];
        #pragma unroll
        for (int i = 0; i < 4; i++)
            b[i] = *(const s16x8*)&Bs[cur][(rB + i * 16) * 32 + kfr];
        #pragma unroll
        for (int mi = 0; mi < MFR; mi++)
            #pragma unroll
            for (int ni = 0; ni < 4; ni++)
                acc[mi][ni] = __builtin_amdgcn_mfma_f32_16x16x32_bf16(
                    a[mi], b[ni], acc[mi][ni], 0, 0, 0);
        __syncthreads();
    }

    float*  Cf = (float*)Cv  + (size_t)z * sC;
    ushort* Cb = (ushort*)Cv + (size_t)z * sC;
    const float* resz = RES ? res + (size_t)z * sC : nullptr;
    #pragma unroll
    for (int ni = 0; ni < 4; ni++) {
        int col = n0 + wc * 64 + ni * 16 + (lane & 15);
        float bv_ = HAS_BIAS ? bias[col] : 0.f;
        #pragma unroll
        for (int mi = 0; mi < MFR; mi++) {
            int rowb = m0 + wr * WROWS + mi * 16 + (lane >> 4) * 4;
            #pragma unroll
            for (int r = 0; r < 4; r++) {
                size_t off = (size_t)(rowb + r) * N + col;
                float vout = (acc[mi][ni][r] + bv_) * alpha;
                if (RES) vout += resz[off];
                if (OUT_BF16) Cb[off] = f2bf(vout);
                else          Cf[off] = vout;
            }
        }
    }
}

// ---------------------------------------------------------------------------
// Row softmax on bf16 S, in place. One block per row (4096 bf16).
// ---------------------------------------------------------------------------
__global__ __launch_bounds__(256) void softmax_bf16(ushort* __restrict__ S) {
    ushort* rp = S + (size_t)blockIdx.x * 4096;
    int t = threadIdx.x;
    s16x8 v0 = ((const s16x8*)rp)[t];
    s16x8 v1 = ((const s16x8*)rp)[t + 256];
    float f[16];
    #pragma unroll
    for (int j = 0; j < 8; j++) { f[j] = bf2f((ushort)v0[j]); f[8 + j] = bf2f((ushort)v1[j]); }

    float m = -1e30f;
    #pragma unroll
    for (int j = 0; j < 16; j++) m = fmaxf(m, f[j]);
    for (int off = 32; off > 0; off >>= 1) m = fmaxf(m, __shfl_xor(m, off));
    __shared__ float red1[4], red2[4];
    int w = t >> 6, lane = t & 63;
    if (lane == 0) red1[w] = m;
    __syncthreads();
    m = fmaxf(fmaxf(red1[0], red1[1]), fmaxf(red1[2], red1[3]));

    float s = 0.f;
    #pragma unroll
    for (int j = 0; j < 16; j++) { f[j] = __expf(f[j] - m); s += f[j]; }
    for (int off = 32; off > 0; off >>= 1) s += __shfl_xor(s, off);
    if (lane == 0) red2[w] = s;
    __syncthreads();
    s = red2[0] + red2[1] + red2[2] + red2[3];
    float inv = 1.f / s;

    s16x8 o0, o1;
    #pragma unroll
    for (int j = 0; j < 8; j++) {
        o0[j] = (short)f2bf(f[j] * inv);
        o1[j] = (short)f2bf(f[8 + j] * inv);
    }
    ((s16x8*)rp)[t] = o0;
    ((s16x8*)rp)[t + 256] = o1;
}

// ---------------------------------------------------------------------------
extern "C" void kernel_launch(void* const* d_in, const int* in_sizes, int n_in,
                              void* d_out, int out_size, void* d_ws, size_t ws_size,
                              hipStream_t stream) {
    const float* x     = (const float*)d_in[0];
    const float* gamma = (const float*)d_in[1];
    const float* beta  = (const float*)d_in[2];
    const float* wq = (const float*)d_in[3];  const float* bq = (const float*)d_in[4];
    const float* wk = (const float*)d_in[5];  const float* bk = (const float*)d_in[6];
    const float* wv = (const float*)d_in[7];  const float* bv = (const float*)d_in[8];
    const float* wp = (const float*)d_in[9];  const float* bp = (const float*)d_in[10];
    float* out = (float*)d_out;

    char* ws = (char*)d_ws;
    size_t off = 0;
    auto alloc = [&](size_t bytes) {
        void* p = ws + off;
        off += (bytes + 255) & ~(size_t)255;
        return p;
    };
    const size_t MTOK = (size_t)4 * 4096;          // 16384 rows
    const size_t QO   = (size_t)4096 * 512;        // per-batch q/k/v elems
    const long long SS = 4096LL * 4096;            // per-batch S elems (bf16)

    float2* stats   = (float2*)alloc(128 * sizeof(float2));
    float2* partial = (float2*)alloc(8192 * sizeof(float2));
    ushort* wtq = (ushort*)alloc(512 * 512 * 2);
    ushort* wtk = (ushort*)alloc(512 * 512 * 2);
    ushort* wtv = (ushort*)alloc(512 * 512 * 2);
    ushort* wtp = (ushort*)alloc(512 * 512 * 2);
    ushort* hb  = (ushort*)alloc(MTOK * 512 * 2);
    ushort* qb  = (ushort*)alloc(MTOK * 512 * 2);
    ushort* kb  = (ushort*)alloc(MTOK * 512 * 2);
    ushort* vb  = (ushort*)alloc(MTOK * 512 * 2);
    ushort* vtb = (ushort*)alloc(MTOK * 512 * 2);
    ushort* Sb  = (ushort*)alloc((size_t)2 * SS * 2);   // 2 batches, bf16, 64MB
    ushort* aob = hb;   // h_ dead after V GEMM; reuse for attn output
    (void)ws_size; (void)in_sizes; (void)n_in; (void)out_size;

    gn_part<<<256, 256, 0, stream>>>(x, partial);
    gn_reduce<<<1, 128, 0, stream>>>(partial, stats);
    gn_apply<<<2048, 256, 0, stream>>>(x, gamma, beta, stats, hb);
    prep_w<<<dim3(16, 16, 4), dim3(32, 8), 0, stream>>>(wq, wk, wv, wp,
                                                        wtq, wtk, wtv, wtp);
    const float scale = 0.044194173824159216f;   // 512^-0.5, folded into q
    gemm_bt<128, true, false, true><<<dim3(4, 128, 1), 256, 0, stream>>>(
        hb, 512, 0, wtq, 0, bq, nullptr, qb, 0, 16384, 512, 512, scale);
    gemm_bt<128, true, false, true><<<dim3(4, 128, 1), 256, 0, stream>>>(
        hb, 512, 0, wtk, 0, bk, nullptr, kb, 0, 16384, 512, 512, 1.f);
    gemm_bt<128, true, false, true><<<dim3(4, 128, 1), 256, 0, stream>>>(
        hb, 512, 0, wtv, 0, bv, nullptr, vb, 0, 16384, 512, 512, 1.f);
    transpose_v<<<dim3(64, 8, 4), 256, 0, stream>>>(vb, vtb);

    for (int p = 0; p < 2; p++) {
        // S = q @ k^T (bf16 out), 2 batches per dispatch
        gemm_bt<128, true, false, false><<<dim3(32, 32, 2), 256, 0, stream>>>(
            qb + (size_t)p * 2 * QO, 512, (long long)QO,
            kb + (size_t)p * 2 * QO, (long long)QO,
            nullptr, nullptr, Sb, SS, 4096, 4096, 512, 1.f);
        // softmax in place over both batches (8192 rows)
        softmax_bf16<<<8192, 256, 0, stream>>>(Sb);
        // O = P @ V^T, BM=64 tile -> 512 blocks
        gemm_bt<64, true, false, false><<<dim3(4, 64, 2), 256, 0, stream>>>(
            Sb, 4096, SS,
            vtb + (size_t)p * 2 * QO, (long long)QO,
            nullptr, nullptr, aob + (size_t)p * 2 * QO, (long long)QO,
            4096, 512, 4096, 1.f);
    }
    gemm_bt<128, false, true, true><<<dim3(4, 128, 1), 256, 0, stream>>>(
        aob, 512, 0, wtp, 0, bp, x, out, 0, 16384, 512, 512, 1.f);
}

// Round 4
// 453.014 us; speedup vs baseline: 1.5801x; 1.0538x over previous
//
#include <hip/hip_runtime.h>
#include <hip/hip_bf16.h>

// ---------------------------------------------------------------------------
// AttnBlock: GroupNorm -> fused qkv 1x1conv -> softmax(QK^T*scale)@V -> proj+res
// B=4, HW=4096, C=512, G=32. bf16 MFMA, fp32 accum.
// Round 4: triple-buffered counted-vmcnt GEMM pipeline (one raw s_barrier +
// vmcnt(4) per K-step, no full drain in-loop), fused QKV (N=1536), z=4
// attention dispatches when workspace allows (fallback: pair loop).
// ---------------------------------------------------------------------------

typedef __attribute__((ext_vector_type(8))) short s16x8;  // 8 bf16
typedef __attribute__((ext_vector_type(4))) float f32x4;  // MFMA accum

__device__ inline ushort f2bf(float f) {
    union { float f; unsigned u; } v; v.f = f;
    unsigned r = (v.u + 0x7FFFu + ((v.u >> 16) & 1u)) >> 16;
    return (ushort)r;
}
__device__ inline float bf2f(ushort u) {
    union { unsigned u; float f; } v; v.u = ((unsigned)u) << 16;
    return v.f;
}

__device__ inline void gll16(const void* g, void* l) {
    __builtin_amdgcn_global_load_lds(
        (const __attribute__((address_space(1))) void*)g,
        (__attribute__((address_space(3))) void*)l, 16, 0, 0);
}

// ---------------------------------------------------------------------------
// GroupNorm stage 1: contiguous partial sums.
// ---------------------------------------------------------------------------
__global__ __launch_bounds__(256) void gn_part(const float* __restrict__ x,
                                               float2* __restrict__ partial) {
    int blk = blockIdx.x;
    int b = blk >> 6, chunk = blk & 63;
    const float* base = x + ((size_t)b * 4096 + chunk * 64) * 512;
    int t = threadIdx.x;
    int q = t & 127, ph = t >> 7;
    float s = 0.f, ss = 0.f;
    for (int p = ph; p < 64; p += 2) {
        float4 v = *(const float4*)(base + (size_t)p * 512 + q * 4);
        s  += v.x + v.y + v.z + v.w;
        ss += v.x * v.x + v.y * v.y + v.z * v.z + v.w * v.w;
    }
    __shared__ float ls[256], lss[256];
    ls[t] = s; lss[t] = ss;
    __syncthreads();
    if (t < 32) {
        float S1 = 0.f, S2 = 0.f;
        #pragma unroll
        for (int j = 0; j < 4; j++) {
            int i = t * 4 + j;
            S1 += ls[i] + ls[i + 128];
            S2 += lss[i] + lss[i + 128];
        }
        partial[(size_t)blk * 32 + t] = make_float2(S1, S2);
    }
}

__global__ void gn_reduce(const float2* __restrict__ partial,
                          float2* __restrict__ stats) {
    int i = threadIdx.x;   // b*32+g
    if (i < 128) {
        int b = i >> 5, g = i & 31;
        float S1 = 0.f, S2 = 0.f;
        for (int c = 0; c < 64; c++) {
            float2 p = partial[((size_t)(b * 64 + c)) * 32 + g];
            S1 += p.x; S2 += p.y;
        }
        float mean = S1 * (1.f / 65536.f);
        float var  = S2 * (1.f / 65536.f) - mean * mean;
        stats[i] = make_float2(mean, rsqrtf(var + 1e-5f));
    }
}

// ---------------------------------------------------------------------------
// GroupNorm apply + cast to bf16 h_
// ---------------------------------------------------------------------------
__global__ __launch_bounds__(256) void gn_apply(const float* __restrict__ x,
                                                const float* __restrict__ gamma,
                                                const float* __restrict__ beta,
                                                const float2* __restrict__ stats,
                                                ushort* __restrict__ h) {
    const int total = 4 * 4096 * 512 / 4;
    for (int i = blockIdx.x * blockDim.x + threadIdx.x; i < total;
         i += gridDim.x * blockDim.x) {
        int e = i * 4;
        int c = e & 511;
        int b = e >> 21;
        int g = c >> 4;
        float2 st = stats[b * 32 + g];
        float4 v  = *(const float4*)(x + (size_t)e);
        float4 ga = *(const float4*)(gamma + c);
        float4 be = *(const float4*)(beta + c);
        ushort4 o;
        o.x = f2bf((v.x - st.x) * st.y * ga.x + be.x);
        o.y = f2bf((v.y - st.x) * st.y * ga.y + be.y);
        o.z = f2bf((v.z - st.x) * st.y * ga.z + be.z);
        o.w = f2bf((v.w - st.x) * st.y * ga.w + be.w);
        ((ushort4*)h)[i] = o;
    }
}

// ---------------------------------------------------------------------------
// Weight prep: fp32 (K,N) -> bf16 (N,K). z<3 -> wcat slab (q scaled), z=3 -> wtp
// ---------------------------------------------------------------------------
__global__ void prep_w(const float* __restrict__ wq, const float* __restrict__ wk,
                       const float* __restrict__ wv, const float* __restrict__ wp,
                       ushort* __restrict__ wcat, ushort* __restrict__ wtp,
                       float qscale) {
    const float* src; ushort* dst; float al = 1.f;
    switch (blockIdx.z) {
        case 0: src = wq; dst = wcat;               al = qscale; break;
        case 1: src = wk; dst = wcat + 512 * 512;   break;
        case 2: src = wv; dst = wcat + 1024 * 512;  break;
        default: src = wp; dst = wtp;               break;
    }
    __shared__ float tile[32][33];
    int k0 = blockIdx.y * 32, n0 = blockIdx.x * 32;
    int tx = threadIdx.x, ty = threadIdx.y;
    #pragma unroll
    for (int i = 0; i < 4; i++)
        tile[ty + i * 8][tx] = src[(size_t)(k0 + ty + i * 8) * 512 + n0 + tx];
    __syncthreads();
    #pragma unroll
    for (int i = 0; i < 4; i++)
        dst[(size_t)(n0 + ty + i * 8) * 512 + k0 + tx] =
            f2bf(tile[tx][ty + i * 8] * al);
}

__global__ void bias_cat(const float* __restrict__ bq, const float* __restrict__ bk,
                         const float* __restrict__ bv, float* __restrict__ bcat,
                         float qscale) {
    int t = threadIdx.x;
    bcat[t]        = bq[t] * qscale;
    bcat[512 + t]  = bk[t];
    bcat[1024 + t] = bv[t];
}

// ---------------------------------------------------------------------------
// V transpose per batch: (4096 x 512, row stride ist) -> (512 x 4096) bf16
// ---------------------------------------------------------------------------
__global__ __launch_bounds__(256) void transpose_v(const ushort* __restrict__ v,
                                                   int ist,
                                                   ushort* __restrict__ vt) {
    __shared__ ushort tile[64][72];
    int b = blockIdx.z;
    int kv0 = blockIdx.x * 64, c0 = blockIdx.y * 64;
    const ushort* in = v + (size_t)b * 4096 * ist;
    ushort* out = vt + (size_t)b * 512 * 4096;
    int t = threadIdx.x;
    int c4 = t & 15, r = t >> 4;
    #pragma unroll
    for (int i = 0; i < 4; i++) {
        int row = r + i * 16;
        *(ushort4*)&tile[row][c4 * 4] =
            *(const ushort4*)(in + (size_t)(kv0 + row) * ist + c0 + c4 * 4);
    }
    __syncthreads();
    int kv4 = t & 15, rc = t >> 4;
    #pragma unroll
    for (int i = 0; i < 4; i++) {
        int c = rc + i * 16;
        ushort4 o;
        o.x = tile[kv4 * 4 + 0][c];
        o.y = tile[kv4 * 4 + 1][c];
        o.z = tile[kv4 * 4 + 2][c];
        o.w = tile[kv4 * 4 + 3][c];
        *(ushort4*)(out + (size_t)(c0 + c) * 4096 + kv0 + kv4 * 4) = o;
    }
}

// ---------------------------------------------------------------------------
// v4-pipe GEMM: C[z][m,n] = (sum_k A[z][m,k]*Bt[z][n,k] + bias[n])*alpha (+res)
// 128x128 tile, BK=32, 256 thr (2x2 waves). Triple-buffered LDS, depth-2
// prefetch, counted s_waitcnt vmcnt(4) + raw s_barrier per K-step (no full
// drain in the main loop). Race-freedom: stage(t+2) -> buf[(t+2)%3] is issued
// only after the iter-t barrier, by which point all waves' ds_reads of that
// slot (K-tile t-1) completed (reads precede each wave's iter-(t-1) MFMAs).
// vmcnt(4) at iter t retires stage(t) (4 loads/thread/stage, FIFO).
// ---------------------------------------------------------------------------
template<bool OUT_BF16, bool RES, bool HAS_BIAS>
__global__ __launch_bounds__(256, 3) void gemm2(
    const ushort* __restrict__ A, int lda, long long sA,
    const ushort* __restrict__ Bt, int ldb, long long sB,
    const float* __restrict__ bias, const float* __restrict__ res,
    void* __restrict__ Cv, long long sC,
    int M, int N, int K, float alpha) {
    __shared__ ushort As[3][128 * 32];
    __shared__ ushort Bs[3][128 * 32];
    int t = threadIdx.x;
    int z = blockIdx.z;
    const ushort* Ab = A  + (size_t)z * sA;
    const ushort* Bb = Bt + (size_t)z * sB;
    int m0 = blockIdx.y * 128, n0 = blockIdx.x * 128;
    int lane = t & 63, w = t >> 6, wr = w >> 1, wc = w & 1;

    f32x4 acc[4][4];
    #pragma unroll
    for (int i = 0; i < 4; i++)
        #pragma unroll
        for (int j = 0; j < 4; j++) acc[i][j] = (f32x4){0.f, 0.f, 0.f, 0.f};

    int kfr = (lane >> 4) * 8;
    int rA = wr * 64 + (lane & 15);
    int rB = wc * 64 + (lane & 15);
    const int NT = K >> 5;

    // stage one K-tile (4 loads/thread: A chunks t, t+256; B chunks t, t+256)
    auto stage = [&](int kt, int buf) {
        int ko = kt * 32;
        #pragma unroll
        for (int i = 0; i < 2; i++) {
            int c = t + i * 256;               // chunk: row c>>2, k-off (c&3)*8
            gll16(Ab + (size_t)(m0 + (c >> 2)) * lda + (c & 3) * 8 + ko,
                  &As[buf][c * 8]);
        }
        #pragma unroll
        for (int i = 0; i < 2; i++) {
            int c = t + i * 256;
            gll16(Bb + (size_t)(n0 + (c >> 2)) * ldb + (c & 3) * 8 + ko,
                  &Bs[buf][c * 8]);
        }
    };

    auto compute = [&](int buf) {
        s16x8 a[4], b[4];
        #pragma unroll
        for (int i = 0; i < 4; i++)
            a[i] = *(const s16x8*)&As[buf][(rA + i * 16) * 32 + kfr];
        #pragma unroll
        for (int i = 0; i < 4; i++)
            b[i] = *(const s16x8*)&Bs[buf][(rB + i * 16) * 32 + kfr];
        #pragma unroll
        for (int mi = 0; mi < 4; mi++)
            #pragma unroll
            for (int ni = 0; ni < 4; ni++)
                acc[mi][ni] = __builtin_amdgcn_mfma_f32_16x16x32_bf16(
                    a[mi], b[ni], acc[mi][ni], 0, 0, 0);
    };

    stage(0, 0);
    stage(1, 1);
    for (int kt = 0; kt < NT - 1; ++kt) {
        // boundary: buf[kt] ready (oldest 4 loads retired); newest 4 in flight
        asm volatile("s_waitcnt vmcnt(4)\n\ts_barrier" ::: "memory");
        if (kt + 2 < NT) stage(kt + 2, (kt + 2) % 3);
        compute(kt % 3);
    }
    asm volatile("s_waitcnt vmcnt(0)\n\ts_barrier" ::: "memory");
    compute((NT - 1) % 3);

    float*  Cf = (float*)Cv  + (size_t)z * sC;
    ushort* Cb = (ushort*)Cv + (size_t)z * sC;
    const float* resz = RES ? res + (size_t)z * sC : nullptr;
    #pragma unroll
    for (int ni = 0; ni < 4; ni++) {
        int col = n0 + wc * 64 + ni * 16 + (lane & 15);
        float bv_ = HAS_BIAS ? bias[col] : 0.f;
        #pragma unroll
        for (int mi = 0; mi < 4; mi++) {
            int rowb = m0 + wr * 64 + mi * 16 + (lane >> 4) * 4;
            #pragma unroll
            for (int r = 0; r < 4; r++) {
                size_t off = (size_t)(rowb + r) * N + col;
                float vout = (acc[mi][ni][r] + bv_) * alpha;
                if (RES) vout += resz[off];
                if (OUT_BF16) Cb[off] = f2bf(vout);
                else          Cf[off] = vout;
            }
        }
    }
}

// ---------------------------------------------------------------------------
// Row softmax on bf16 S, in place. One block per row (4096 bf16).
// ---------------------------------------------------------------------------
__global__ __launch_bounds__(256) void softmax_bf16(ushort* __restrict__ S) {
    ushort* rp = S + (size_t)blockIdx.x * 4096;
    int t = threadIdx.x;
    s16x8 v0 = ((const s16x8*)rp)[t];
    s16x8 v1 = ((const s16x8*)rp)[t + 256];
    float f[16];
    #pragma unroll
    for (int j = 0; j < 8; j++) { f[j] = bf2f((ushort)v0[j]); f[8 + j] = bf2f((ushort)v1[j]); }

    float m = -1e30f;
    #pragma unroll
    for (int j = 0; j < 16; j++) m = fmaxf(m, f[j]);
    for (int off = 32; off > 0; off >>= 1) m = fmaxf(m, __shfl_xor(m, off));
    __shared__ float red1[4], red2[4];
    int w = t >> 6, lane = t & 63;
    if (lane == 0) red1[w] = m;
    __syncthreads();
    m = fmaxf(fmaxf(red1[0], red1[1]), fmaxf(red1[2], red1[3]));

    float s = 0.f;
    #pragma unroll
    for (int j = 0; j < 16; j++) { f[j] = __expf(f[j] - m); s += f[j]; }
    for (int off = 32; off > 0; off >>= 1) s += __shfl_xor(s, off);
    if (lane == 0) red2[w] = s;
    __syncthreads();
    s = red2[0] + red2[1] + red2[2] + red2[3];
    float inv = 1.f / s;

    s16x8 o0, o1;
    #pragma unroll
    for (int j = 0; j < 8; j++) {
        o0[j] = (short)f2bf(f[j] * inv);
        o1[j] = (short)f2bf(f[8 + j] * inv);
    }
    ((s16x8*)rp)[t] = o0;
    ((s16x8*)rp)[t + 256] = o1;
}

// ---------------------------------------------------------------------------
extern "C" void kernel_launch(void* const* d_in, const int* in_sizes, int n_in,
                              void* d_out, int out_size, void* d_ws, size_t ws_size,
                              hipStream_t stream) {
    const float* x     = (const float*)d_in[0];
    const float* gamma = (const float*)d_in[1];
    const float* beta  = (const float*)d_in[2];
    const float* wq = (const float*)d_in[3];  const float* bq = (const float*)d_in[4];
    const float* wk = (const float*)d_in[5];  const float* bk = (const float*)d_in[6];
    const float* wv = (const float*)d_in[7];  const float* bv = (const float*)d_in[8];
    const float* wp = (const float*)d_in[9];  const float* bp = (const float*)d_in[10];
    float* out = (float*)d_out;

    char* ws = (char*)d_ws;
    size_t off = 0;
    auto alloc = [&](size_t bytes) {
        void* p = ws + off;
        off += (bytes + 255) & ~(size_t)255;
        return p;
    };
    const long long QO  = 4096LL * 512;          // per-batch attn-out elems
    const long long SS  = 4096LL * 4096;         // per-batch S elems (bf16)
    const long long QSA = 4096LL * 1536;         // per-batch qkv row stride

    float2* stats   = (float2*)alloc(128 * sizeof(float2));
    float2* partial = (float2*)alloc(8192 * sizeof(float2));
    ushort* wcat = (ushort*)alloc((size_t)1536 * 512 * 2);
    ushort* wtp  = (ushort*)alloc((size_t)512 * 512 * 2);
    float*  bcat = (float*)alloc(1536 * sizeof(float));
    ushort* hb   = (ushort*)alloc((size_t)16384 * 512 * 2);   // h_, later attn out
    ushort* qkvb = (ushort*)alloc((size_t)16384 * 1536 * 2);  // fused q|k|v
    ushort* vtb  = (ushort*)alloc((size_t)16384 * 512 * 2);
    bool big = ws_size >= (off + (size_t)4 * SS * 2 + (1 << 20));
    ushort* Sb = (ushort*)alloc(((size_t)(big ? 4 : 2)) * SS * 2);
    ushort* aob = hb;
    (void)in_sizes; (void)n_in; (void)out_size;

    const float scale = 0.044194173824159216f;   // 512^-0.5, folded into wq/bq

    gn_part<<<256, 256, 0, stream>>>(x, partial);
    gn_reduce<<<1, 128, 0, stream>>>(partial, stats);
    gn_apply<<<2048, 256, 0, stream>>>(x, gamma, beta, stats, hb);
    prep_w<<<dim3(16, 16, 4), dim3(32, 8), 0, stream>>>(wq, wk, wv, wp,
                                                        wcat, wtp, scale);
    bias_cat<<<1, 512, 0, stream>>>(bq, bk, bv, bcat, scale);

    // fused QKV: [16384 x 1536] = h_ @ wcat^T + bcat
    gemm2<true, false, true><<<dim3(12, 128, 1), 256, 0, stream>>>(
        hb, 512, 0, wcat, 512, 0, bcat, nullptr, qkvb, 0,
        16384, 1536, 512, 1.f);
    transpose_v<<<dim3(64, 8, 4), 256, 0, stream>>>(qkvb + 1024, 1536, vtb);

    if (big) {
        gemm2<true, false, false><<<dim3(32, 32, 4), 256, 0, stream>>>(
            qkvb, 1536, QSA, qkvb + 512, 1536, QSA,
            nullptr, nullptr, Sb, SS, 4096, 4096, 512, 1.f);
        softmax_bf16<<<16384, 256, 0, stream>>>(Sb);
        gemm2<true, false, false><<<dim3(4, 32, 4), 256, 0, stream>>>(
            Sb, 4096, SS, vtb, 4096, QO,
            nullptr, nullptr, aob, QO, 4096, 512, 4096, 1.f);
    } else {
        for (int p = 0; p < 2; p++) {
            gemm2<true, false, false><<<dim3(32, 32, 2), 256, 0, stream>>>(
                qkvb + (size_t)p * 2 * QSA, 1536, QSA,
                qkvb + 512 + (size_t)p * 2 * QSA, 1536, QSA,
                nullptr, nullptr, Sb, SS, 4096, 4096, 512, 1.f);
            softmax_bf16<<<8192, 256, 0, stream>>>(Sb);
            gemm2<true, false, false><<<dim3(4, 32, 2), 256, 0, stream>>>(
                Sb, 4096, SS, vtb + (size_t)p * 2 * QO, 4096, QO,
                nullptr, nullptr, aob + (size_t)p * 2 * QO, QO,
                4096, 512, 4096, 1.f);
        }
    }
    gemm2<false, true, true><<<dim3(4, 128, 1), 256, 0, stream>>>(
        aob, 512, 0, wtp, 512, 0, bp, x, out, 0, 16384, 512, 512, 1.f);
}

// Round 5
// 421.704 us; speedup vs baseline: 1.6974x; 1.0742x over previous
//
#include <hip/hip_runtime.h>
#include <hip/hip_bf16.h>

// ---------------------------------------------------------------------------
// AttnBlock: GroupNorm -> fused qkv 1x1conv -> softmax(QK^T*scale)@V -> proj+res
// B=4, HW=4096, C=512, G=32. bf16 MFMA, fp32 accum.
// Round 5: + T2 LDS swizzle (pre-swizzled global source, swizzled ds_read;
// involution g ^= (row>>1)&3 kills the 8-way bank conflict) and T1 bijective
// XCD-aware blockIdx swizzle in gemm2. Pipeline structure unchanged (3-buf,
// depth-2, counted vmcnt(4) + raw s_barrier per K-step).
// ---------------------------------------------------------------------------

typedef __attribute__((ext_vector_type(8))) short s16x8;  // 8 bf16
typedef __attribute__((ext_vector_type(4))) float f32x4;  // MFMA accum

__device__ inline ushort f2bf(float f) {
    union { float f; unsigned u; } v; v.f = f;
    unsigned r = (v.u + 0x7FFFu + ((v.u >> 16) & 1u)) >> 16;
    return (ushort)r;
}
__device__ inline float bf2f(ushort u) {
    union { unsigned u; float f; } v; v.u = ((unsigned)u) << 16;
    return v.f;
}

__device__ inline void gll16(const void* g, void* l) {
    __builtin_amdgcn_global_load_lds(
        (const __attribute__((address_space(1))) void*)g,
        (__attribute__((address_space(3))) void*)l, 16, 0, 0);
}

// ---------------------------------------------------------------------------
// GroupNorm stage 1: contiguous partial sums.
// ---------------------------------------------------------------------------
__global__ __launch_bounds__(256) void gn_part(const float* __restrict__ x,
                                               float2* __restrict__ partial) {
    int blk = blockIdx.x;
    int b = blk >> 6, chunk = blk & 63;
    const float* base = x + ((size_t)b * 4096 + chunk * 64) * 512;
    int t = threadIdx.x;
    int q = t & 127, ph = t >> 7;
    float s = 0.f, ss = 0.f;
    for (int p = ph; p < 64; p += 2) {
        float4 v = *(const float4*)(base + (size_t)p * 512 + q * 4);
        s  += v.x + v.y + v.z + v.w;
        ss += v.x * v.x + v.y * v.y + v.z * v.z + v.w * v.w;
    }
    __shared__ float ls[256], lss[256];
    ls[t] = s; lss[t] = ss;
    __syncthreads();
    if (t < 32) {
        float S1 = 0.f, S2 = 0.f;
        #pragma unroll
        for (int j = 0; j < 4; j++) {
            int i = t * 4 + j;
            S1 += ls[i] + ls[i + 128];
            S2 += lss[i] + lss[i + 128];
        }
        partial[(size_t)blk * 32 + t] = make_float2(S1, S2);
    }
}

__global__ void gn_reduce(const float2* __restrict__ partial,
                          float2* __restrict__ stats) {
    int i = threadIdx.x;   // b*32+g
    if (i < 128) {
        int b = i >> 5, g = i & 31;
        float S1 = 0.f, S2 = 0.f;
        for (int c = 0; c < 64; c++) {
            float2 p = partial[((size_t)(b * 64 + c)) * 32 + g];
            S1 += p.x; S2 += p.y;
        }
        float mean = S1 * (1.f / 65536.f);
        float var  = S2 * (1.f / 65536.f) - mean * mean;
        stats[i] = make_float2(mean, rsqrtf(var + 1e-5f));
    }
}

// ---------------------------------------------------------------------------
// GroupNorm apply + cast to bf16 h_
// ---------------------------------------------------------------------------
__global__ __launch_bounds__(256) void gn_apply(const float* __restrict__ x,
                                                const float* __restrict__ gamma,
                                                const float* __restrict__ beta,
                                                const float2* __restrict__ stats,
                                                ushort* __restrict__ h) {
    const int total = 4 * 4096 * 512 / 4;
    for (int i = blockIdx.x * blockDim.x + threadIdx.x; i < total;
         i += gridDim.x * blockDim.x) {
        int e = i * 4;
        int c = e & 511;
        int b = e >> 21;
        int g = c >> 4;
        float2 st = stats[b * 32 + g];
        float4 v  = *(const float4*)(x + (size_t)e);
        float4 ga = *(const float4*)(gamma + c);
        float4 be = *(const float4*)(beta + c);
        ushort4 o;
        o.x = f2bf((v.x - st.x) * st.y * ga.x + be.x);
        o.y = f2bf((v.y - st.x) * st.y * ga.y + be.y);
        o.z = f2bf((v.z - st.x) * st.y * ga.z + be.z);
        o.w = f2bf((v.w - st.x) * st.y * ga.w + be.w);
        ((ushort4*)h)[i] = o;
    }
}

// ---------------------------------------------------------------------------
// Weight prep: fp32 (K,N) -> bf16 (N,K). z<3 -> wcat slab (q scaled), z=3 -> wtp
// ---------------------------------------------------------------------------
__global__ void prep_w(const float* __restrict__ wq, const float* __restrict__ wk,
                       const float* __restrict__ wv, const float* __restrict__ wp,
                       ushort* __restrict__ wcat, ushort* __restrict__ wtp,
                       float qscale) {
    const float* src; ushort* dst; float al = 1.f;
    switch (blockIdx.z) {
        case 0: src = wq; dst = wcat;               al = qscale; break;
        case 1: src = wk; dst = wcat + 512 * 512;   break;
        case 2: src = wv; dst = wcat + 1024 * 512;  break;
        default: src = wp; dst = wtp;               break;
    }
    __shared__ float tile[32][33];
    int k0 = blockIdx.y * 32, n0 = blockIdx.x * 32;
    int tx = threadIdx.x, ty = threadIdx.y;
    #pragma unroll
    for (int i = 0; i < 4; i++)
        tile[ty + i * 8][tx] = src[(size_t)(k0 + ty + i * 8) * 512 + n0 + tx];
    __syncthreads();
    #pragma unroll
    for (int i = 0; i < 4; i++)
        dst[(size_t)(n0 + ty + i * 8) * 512 + k0 + tx] =
            f2bf(tile[tx][ty + i * 8] * al);
}

__global__ void bias_cat(const float* __restrict__ bq, const float* __restrict__ bk,
                         const float* __restrict__ bv, float* __restrict__ bcat,
                         float qscale) {
    int t = threadIdx.x;
    bcat[t]        = bq[t] * qscale;
    bcat[512 + t]  = bk[t];
    bcat[1024 + t] = bv[t];
}

// ---------------------------------------------------------------------------
// V transpose per batch: (4096 x 512, row stride ist) -> (512 x 4096) bf16
// ---------------------------------------------------------------------------
__global__ __launch_bounds__(256) void transpose_v(const ushort* __restrict__ v,
                                                   int ist,
                                                   ushort* __restrict__ vt) {
    __shared__ ushort tile[64][72];
    int b = blockIdx.z;
    int kv0 = blockIdx.x * 64, c0 = blockIdx.y * 64;
    const ushort* in = v + (size_t)b * 4096 * ist;
    ushort* out = vt + (size_t)b * 512 * 4096;
    int t = threadIdx.x;
    int c4 = t & 15, r = t >> 4;
    #pragma unroll
    for (int i = 0; i < 4; i++) {
        int row = r + i * 16;
        *(ushort4*)&tile[row][c4 * 4] =
            *(const ushort4*)(in + (size_t)(kv0 + row) * ist + c0 + c4 * 4);
    }
    __syncthreads();
    int kv4 = t & 15, rc = t >> 4;
    #pragma unroll
    for (int i = 0; i < 4; i++) {
        int c = rc + i * 16;
        ushort4 o;
        o.x = tile[kv4 * 4 + 0][c];
        o.y = tile[kv4 * 4 + 1][c];
        o.z = tile[kv4 * 4 + 2][c];
        o.w = tile[kv4 * 4 + 3][c];
        *(ushort4*)(out + (size_t)(c0 + c) * 4096 + kv0 + kv4 * 4) = o;
    }
}

// ---------------------------------------------------------------------------
// v5-pipe GEMM: C[z][m,n] = (sum_k A[z][m,k]*Bt[z][n,k] + bias[n])*alpha (+res)
// 128x128 tile, BK=32, 256 thr (2x2 waves). Triple-buffered LDS, depth-2
// prefetch, counted s_waitcnt vmcnt(4) + raw s_barrier per K-step.
// T2: LDS k-quad swizzle g ^= (row>>1)&3, applied identically on the staging
// SOURCE address (LDS dest stays linear, per global_load_lds rules) and the
// ds_read address -> lanes 0..15 spread over all 8 bank quads (2-way, free).
// T1: bijective XCD remap of the (x,y) plane (requires gx*gy % 8 == 0).
// ---------------------------------------------------------------------------
template<bool OUT_BF16, bool RES, bool HAS_BIAS>
__global__ __launch_bounds__(256, 3) void gemm2(
    const ushort* __restrict__ A, int lda, long long sA,
    const ushort* __restrict__ Bt, int ldb, long long sB,
    const float* __restrict__ bias, const float* __restrict__ res,
    void* __restrict__ Cv, long long sC,
    int M, int N, int K, float alpha) {
    __shared__ ushort As[3][128 * 32];
    __shared__ ushort Bs[3][128 * 32];
    int t = threadIdx.x;
    int z = blockIdx.z;

    // T1: XCD-aware remap within the (x,y) plane. XCD = linear_id % 8; give
    // each XCD a contiguous chunk of the y-major linearization.
    int gx = gridDim.x;
    int lin = blockIdx.y * gx + blockIdx.x;
    int nwg = gx * gridDim.y;
    int swz = (lin & 7) * (nwg >> 3) + (lin >> 3);
    int bx = swz % gx, by = swz / gx;

    const ushort* Ab = A  + (size_t)z * sA;
    const ushort* Bb = Bt + (size_t)z * sB;
    int m0 = by * 128, n0 = bx * 128;
    int lane = t & 63, w = t >> 6, wr = w >> 1, wc = w & 1;

    f32x4 acc[4][4];
    #pragma unroll
    for (int i = 0; i < 4; i++)
        #pragma unroll
        for (int j = 0; j < 4; j++) acc[i][j] = (f32x4){0.f, 0.f, 0.f, 0.f};

    int kq = lane >> 4;              // logical k-quad 0..3 (8 ushorts each)
    int rA = wr * 64 + (lane & 15);
    int rB = wc * 64 + (lane & 15);
    const int NT = K >> 5;

    // stage one K-tile; LDS slot (row, g) gets global k-part g^((row>>1)&3)
    auto stage = [&](int kt, int buf) {
        int ko = kt * 32;
        #pragma unroll
        for (int i = 0; i < 2; i++) {
            int c = t + i * 256;
            int row = c >> 2, g = (c & 3) ^ ((row >> 1) & 3);
            gll16(Ab + (size_t)(m0 + row) * lda + g * 8 + ko, &As[buf][c * 8]);
        }
        #pragma unroll
        for (int i = 0; i < 2; i++) {
            int c = t + i * 256;
            int row = c >> 2, g = (c & 3) ^ ((row >> 1) & 3);
            gll16(Bb + (size_t)(n0 + row) * ldb + g * 8 + ko, &Bs[buf][c * 8]);
        }
    };

    auto compute = [&](int buf) {
        s16x8 a[4], b[4];
        #pragma unroll
        for (int i = 0; i < 4; i++) {
            int row = rA + i * 16;
            int pg = kq ^ ((row >> 1) & 3);
            a[i] = *(const s16x8*)&As[buf][row * 32 + pg * 8];
        }
        #pragma unroll
        for (int i = 0; i < 4; i++) {
            int row = rB + i * 16;
            int pg = kq ^ ((row >> 1) & 3);
            b[i] = *(const s16x8*)&Bs[buf][row * 32 + pg * 8];
        }
        #pragma unroll
        for (int mi = 0; mi < 4; mi++)
            #pragma unroll
            for (int ni = 0; ni < 4; ni++)
                acc[mi][ni] = __builtin_amdgcn_mfma_f32_16x16x32_bf16(
                    a[mi], b[ni], acc[mi][ni], 0, 0, 0);
    };

    stage(0, 0);
    stage(1, 1);
    for (int kt = 0; kt < NT - 1; ++kt) {
        // boundary: buf[kt] ready (oldest 4 loads retired); newest 4 in flight
        asm volatile("s_waitcnt vmcnt(4)\n\ts_barrier" ::: "memory");
        if (kt + 2 < NT) stage(kt + 2, (kt + 2) % 3);
        compute(kt % 3);
    }
    asm volatile("s_waitcnt vmcnt(0)\n\ts_barrier" ::: "memory");
    compute((NT - 1) % 3);

    float*  Cf = (float*)Cv  + (size_t)z * sC;
    ushort* Cb = (ushort*)Cv + (size_t)z * sC;
    const float* resz = RES ? res + (size_t)z * sC : nullptr;
    #pragma unroll
    for (int ni = 0; ni < 4; ni++) {
        int col = n0 + wc * 64 + ni * 16 + (lane & 15);
        float bv_ = HAS_BIAS ? bias[col] : 0.f;
        #pragma unroll
        for (int mi = 0; mi < 4; mi++) {
            int rowb = m0 + wr * 64 + mi * 16 + (lane >> 4) * 4;
            #pragma unroll
            for (int r = 0; r < 4; r++) {
                size_t off = (size_t)(rowb + r) * N + col;
                float vout = (acc[mi][ni][r] + bv_) * alpha;
                if (RES) vout += resz[off];
                if (OUT_BF16) Cb[off] = f2bf(vout);
                else          Cf[off] = vout;
            }
        }
    }
}

// ---------------------------------------------------------------------------
// Row softmax on bf16 S, in place. One block per row (4096 bf16).
// ---------------------------------------------------------------------------
__global__ __launch_bounds__(256) void softmax_bf16(ushort* __restrict__ S) {
    ushort* rp = S + (size_t)blockIdx.x * 4096;
    int t = threadIdx.x;
    s16x8 v0 = ((const s16x8*)rp)[t];
    s16x8 v1 = ((const s16x8*)rp)[t + 256];
    float f[16];
    #pragma unroll
    for (int j = 0; j < 8; j++) { f[j] = bf2f((ushort)v0[j]); f[8 + j] = bf2f((ushort)v1[j]); }

    float m = -1e30f;
    #pragma unroll
    for (int j = 0; j < 16; j++) m = fmaxf(m, f[j]);
    for (int off = 32; off > 0; off >>= 1) m = fmaxf(m, __shfl_xor(m, off));
    __shared__ float red1[4], red2[4];
    int w = t >> 6, lane = t & 63;
    if (lane == 0) red1[w] = m;
    __syncthreads();
    m = fmaxf(fmaxf(red1[0], red1[1]), fmaxf(red1[2], red1[3]));

    float s = 0.f;
    #pragma unroll
    for (int j = 0; j < 16; j++) { f[j] = __expf(f[j] - m); s += f[j]; }
    for (int off = 32; off > 0; off >>= 1) s += __shfl_xor(s, off);
    if (lane == 0) red2[w] = s;
    __syncthreads();
    s = red2[0] + red2[1] + red2[2] + red2[3];
    float inv = 1.f / s;

    s16x8 o0, o1;
    #pragma unroll
    for (int j = 0; j < 8; j++) {
        o0[j] = (short)f2bf(f[j] * inv);
        o1[j] = (short)f2bf(f[8 + j] * inv);
    }
    ((s16x8*)rp)[t] = o0;
    ((s16x8*)rp)[t + 256] = o1;
}

// ---------------------------------------------------------------------------
extern "C" void kernel_launch(void* const* d_in, const int* in_sizes, int n_in,
                              void* d_out, int out_size, void* d_ws, size_t ws_size,
                              hipStream_t stream) {
    const float* x     = (const float*)d_in[0];
    const float* gamma = (const float*)d_in[1];
    const float* beta  = (const float*)d_in[2];
    const float* wq = (const float*)d_in[3];  const float* bq = (const float*)d_in[4];
    const float* wk = (const float*)d_in[5];  const float* bk = (const float*)d_in[6];
    const float* wv = (const float*)d_in[7];  const float* bv = (const float*)d_in[8];
    const float* wp = (const float*)d_in[9];  const float* bp = (const float*)d_in[10];
    float* out = (float*)d_out;

    char* ws = (char*)d_ws;
    size_t off = 0;
    auto alloc = [&](size_t bytes) {
        void* p = ws + off;
        off += (bytes + 255) & ~(size_t)255;
        return p;
    };
    const long long QO  = 4096LL * 512;          // per-batch attn-out elems
    const long long SS  = 4096LL * 4096;         // per-batch S elems (bf16)
    const long long QSA = 4096LL * 1536;         // per-batch qkv row stride

    float2* stats   = (float2*)alloc(128 * sizeof(float2));
    float2* partial = (float2*)alloc(8192 * sizeof(float2));
    ushort* wcat = (ushort*)alloc((size_t)1536 * 512 * 2);
    ushort* wtp  = (ushort*)alloc((size_t)512 * 512 * 2);
    float*  bcat = (float*)alloc(1536 * sizeof(float));
    ushort* hb   = (ushort*)alloc((size_t)16384 * 512 * 2);   // h_, later attn out
    ushort* qkvb = (ushort*)alloc((size_t)16384 * 1536 * 2);  // fused q|k|v
    ushort* vtb  = (ushort*)alloc((size_t)16384 * 512 * 2);
    bool big = ws_size >= (off + (size_t)4 * SS * 2 + (1 << 20));
    ushort* Sb = (ushort*)alloc(((size_t)(big ? 4 : 2)) * SS * 2);
    ushort* aob = hb;
    (void)in_sizes; (void)n_in; (void)out_size;

    const float scale = 0.044194173824159216f;   // 512^-0.5, folded into wq/bq

    gn_part<<<256, 256, 0, stream>>>(x, partial);
    gn_reduce<<<1, 128, 0, stream>>>(partial, stats);
    gn_apply<<<2048, 256, 0, stream>>>(x, gamma, beta, stats, hb);
    prep_w<<<dim3(16, 16, 4), dim3(32, 8), 0, stream>>>(wq, wk, wv, wp,
                                                        wcat, wtp, scale);
    bias_cat<<<1, 512, 0, stream>>>(bq, bk, bv, bcat, scale);

    // fused QKV: [16384 x 1536] = h_ @ wcat^T + bcat
    gemm2<true, false, true><<<dim3(12, 128, 1), 256, 0, stream>>>(
        hb, 512, 0, wcat, 512, 0, bcat, nullptr, qkvb, 0,
        16384, 1536, 512, 1.f);
    transpose_v<<<dim3(64, 8, 4), 256, 0, stream>>>(qkvb + 1024, 1536, vtb);

    if (big) {
        gemm2<true, false, false><<<dim3(32, 32, 4), 256, 0, stream>>>(
            qkvb, 1536, QSA, qkvb + 512, 1536, QSA,
            nullptr, nullptr, Sb, SS, 4096, 4096, 512, 1.f);
        softmax_bf16<<<16384, 256, 0, stream>>>(Sb);
        gemm2<true, false, false><<<dim3(4, 32, 4), 256, 0, stream>>>(
            Sb, 4096, SS, vtb, 4096, QO,
            nullptr, nullptr, aob, QO, 4096, 512, 4096, 1.f);
    } else {
        for (int p = 0; p < 2; p++) {
            gemm2<true, false, false><<<dim3(32, 32, 2), 256, 0, stream>>>(
                qkvb + (size_t)p * 2 * QSA, 1536, QSA,
                qkvb + 512 + (size_t)p * 2 * QSA, 1536, QSA,
                nullptr, nullptr, Sb, SS, 4096, 4096, 512, 1.f);
            softmax_bf16<<<8192, 256, 0, stream>>>(Sb);
            gemm2<true, false, false><<<dim3(4, 32, 2), 256, 0, stream>>>(
                Sb, 4096, SS, vtb + (size_t)p * 2 * QO, 4096, QO,
                nullptr, nullptr, aob + (size_t)p * 2 * QO, QO,
                4096, 512, 4096, 1.f);
        }
    }
    gemm2<false, true, true><<<dim3(4, 128, 1), 256, 0, stream>>>(
        aob, 512, 0, wtp, 512, 0, bp, x, out, 0, 16384, 512, 512, 1.f);
}